// Round 1
// baseline (277.614 us; speedup 1.0000x reference)
//
#include <hip/hip_runtime.h>
#include <stdint.h>

#define PP 196            // 14*14
#define BP 6272           // 32*196

typedef _Float16 half_t;
typedef half_t half8v __attribute__((ext_vector_type(8)));
typedef half_t half2v __attribute__((ext_vector_type(2)));

// DMA one 16B element per lane: global (per-lane addr) -> LDS (wave-uniform
// base, HW adds lane*16). Counts in vmcnt.
__device__ __forceinline__ void dma16(const float* g, float* l) {
  __builtin_amdgcn_global_load_lds(
      (const __attribute__((address_space(1))) float*)g,
      (__attribute__((address_space(3))) float*)l, 16, 0, 0);
}

// ---------------------------------------------------------------------------
// assign kernels (layers 1,2): nearest-centroid 4-bit indices, packed 8/u32.
// f32 SCREEN + f64 FIXUP (R7-proven): screen tracks best/second-best; iff any
// lane's gap < TAU the wave re-runs that codebook with the exact f64 formula.
// idx layout: idxp[cb/8][BP]
// ---------------------------------------------------------------------------

template <typename T>
__global__ __launch_bounds__(256) void assign_1x1(
    const T* __restrict__ in, const float* __restrict__ cents,
    uint32_t* __restrict__ idxp, int nchan) {
  __shared__ float  sf[8][16][4];     // screen rows (16 B, one b128)
  __shared__ double sd[8][16][6];     // [c2, c0..c3, pad]: 48 B rows
  const int chunk = blockIdx.y;
  const int t = threadIdx.x;
  for (int i = t; i < 512; i += 256) {
    float c = cents[(size_t)chunk * 512 + i];
    int cb = i >> 6, r = i & 63;      // r = k*4 + d
    sf[cb][r >> 2][r & 3] = c;
    sd[cb][r >> 2][1 + (r & 3)] = (double)c;
  }
  __syncthreads();
  if (t < 128) {
    int cb = t >> 4, k = t & 15;
    double s = 0.0;
#pragma unroll
    for (int d = 0; d < 4; d++) { double c = sd[cb][k][1 + d]; s += c * c; }
    sd[cb][k][0] = s;
  }
  __syncthreads();
  const int p = blockIdx.x * 256 + t;
  if (p >= BP) return;
  const unsigned b = (unsigned)p / 196u;
  const unsigned pr = (unsigned)p - b * 196u;
  const T* xb = in + ((size_t)b * nchan + chunk * 32) * PP + pr;
  T xr[32];
#pragma unroll
  for (int i = 0; i < 32; i++) xr[i] = xb[(size_t)i * PP];
  float xs2[32];
#pragma unroll
  for (int i = 0; i < 32; i++) xs2[i] = 2.f * (float)xr[i];
  uint32_t word = 0;
#pragma unroll 1
  for (int cb = 0; cb < 8; cb++) {
    float best = 1e30f, sec = 1e30f; int bi = 0;
#pragma unroll
    for (int k = 0; k < 16; k++) {
      const float4 c = *(const float4*)&sf[cb][k][0];
      float dist = c.x * (c.x - xs2[cb * 4 + 0]);
      dist = fmaf(c.y, c.y - xs2[cb * 4 + 1], dist);
      dist = fmaf(c.z, c.z - xs2[cb * 4 + 2], dist);
      dist = fmaf(c.w, c.w - xs2[cb * 4 + 3], dist);
      if (dist < best) { sec = best; best = dist; bi = k; }
      else sec = fminf(sec, dist);
    }
    if (__any(sec - best < 2e-4f)) {
      double xv[4];
#pragma unroll
      for (int d = 0; d < 4; d++) xv[d] = (double)xr[cb * 4 + d];
      double bb = 1e300; int bi64 = 0;
#pragma unroll
      for (int k = 0; k < 16; k++) {
        double dot = 0.0;
#pragma unroll
        for (int d = 0; d < 4; d++) dot = fma(xv[d], sd[cb][k][1 + d], dot);
        double dist = sd[cb][k][0] - 2.0 * dot;
        if (dist < bb) { bb = dist; bi64 = k; }   // strict <: first-min
      }
      bi = bi64;
    }
    word |= (uint32_t)bi << (4 * cb);
  }
  idxp[(size_t)chunk * BP + p] = word;
}

__global__ __launch_bounds__(256) void assign_3x3(
    const double* __restrict__ in, const float* __restrict__ cents,
    uint32_t* __restrict__ idxp) {
  __shared__ float  sf[8][16][12];    // [c2f, c0..c8, pad, pad]: 48 B rows
  __shared__ double sd[8][16][10];    // [c2, c0..c8]: 80 B rows
  const int chunk = blockIdx.y;
  const int c0g = chunk * 8;
  const int t = threadIdx.x;
  for (int i = t; i < 1152; i += 256) {
    int cb = i / 144, r = i - cb * 144;
    int k = r / 9, d = r - k * 9;
    float c = cents[(size_t)(c0g + cb) * 144 + k * 9 + d];
    sf[cb][k][1 + d] = c;
    sd[cb][k][1 + d] = (double)c;
  }
  __syncthreads();
  if (t < 128) {
    int cb = t >> 4, k = t & 15;
    double s = 0.0;
    float s32 = 0.f;
#pragma unroll
    for (int d = 0; d < 9; d++) {
      double c = sd[cb][k][1 + d]; s += c * c;
      float cf = sf[cb][k][1 + d]; s32 += cf * cf;
    }
    sd[cb][k][0] = s;
    sf[cb][k][0] = s32;
  }
  __syncthreads();
  const int p = blockIdx.x * 256 + t;
  if (p >= BP) return;
  const unsigned b = (unsigned)p / 196u;
  const unsigned pr = (unsigned)p - b * 196u;
  const int oh = pr / 14, ow = pr - oh * 14;
  uint32_t word = 0;
#pragma unroll 1
  for (int cb = 0; cb < 8; cb++) {
    const double* base = in + ((size_t)b * 256 + (c0g + cb)) * PP;
    double v64[9]; float v32[9];
#pragma unroll
    for (int r = 0; r < 3; r++) {
#pragma unroll
      for (int cc = 0; cc < 3; cc++) {
        int hh = oh + r - 1, ww = ow + cc - 1;
        bool ok = (hh >= 0) & (hh < 14) & (ww >= 0) & (ww < 14);
        double v = ok ? base[hh * 14 + ww] : 0.0;
        v64[r * 3 + cc] = v;
        v32[r * 3 + cc] = (float)v;
      }
    }
    float best = 1e30f, sec = 1e30f; int bi = 0;
#pragma unroll
    for (int k = 0; k < 16; k++) {
      const float4 cA = *(const float4*)&sf[cb][k][0];  // c2f,c0,c1,c2
      const float4 cB = *(const float4*)&sf[cb][k][4];  // c3..c6
      const float4 cC = *(const float4*)&sf[cb][k][8];  // c7,c8,pad,pad
      float dot = v32[0] * cA.y;
      dot = fmaf(v32[1], cA.z, dot);
      dot = fmaf(v32[2], cA.w, dot);
      dot = fmaf(v32[3], cB.x, dot);
      dot = fmaf(v32[4], cB.y, dot);
      dot = fmaf(v32[5], cB.z, dot);
      dot = fmaf(v32[6], cB.w, dot);
      dot = fmaf(v32[7], cC.x, dot);
      dot = fmaf(v32[8], cC.y, dot);
      float dist = fmaf(-2.f, dot, cA.x);
      if (dist < best) { sec = best; best = dist; bi = k; }
      else sec = fminf(sec, dist);
    }
    if (__any(sec - best < 4e-4f)) {
      double bb = 1e300; int bi64 = 0;
#pragma unroll
      for (int k = 0; k < 16; k++) {
        double dot = 0.0;
#pragma unroll
        for (int d = 0; d < 9; d++) dot = fma(v64[d], sd[cb][k][1 + d], dot);
        double dist = sd[cb][k][0] - 2.0 * dot;
        if (dist < bb) { bb = dist; bi64 = k; }
      }
      bi = bi64;
    }
    word |= (uint32_t)bi << (4 * cb);
  }
  idxp[(size_t)chunk * BP + p] = word;
}

// ---------------------------------------------------------------------------
// accum v3 (f64-grade, DMA-staged): out = act(scale*sum_cb lut[cb][idx][o] +
// bias) per (pos, 16 ch). 256-thread blocks (64 pos x 16 ch; q = wave =
// channel quad), grid (98, 16).
// LDS-pipe was the bound (R0 counters: ~92% of runtime = ds_read 75K +
// ds_write 19K + write-conflict 13K cy/CU). v3 removes the ds_write path:
//  - global_load_lds DMA staging (no wave LDS-issue cycles, linear
//    conflict-free writes). Dest must be linear (m104/m173), so the slot
//    layout is TRANSPOSED: slot = cb*64 + q*16 + k (16 B slots); the per-lane
//    *global source* address carries the permutation. Gather bank-quad =
//    k mod 8 -> 2-way = free (m136). No padding needed.
//  - 8-cb chunks (one packed idx word each), double-buffered 2 x 8 KB;
//    counted s_waitcnt vmcnt(2) + raw s_barrier keeps next chunk's DMA in
//    flight across the barrier (no vmcnt(0) drain in the loop).
// PAIRWISE accumulation: adjacent cb pairs summed in f32 (err ~7e-7 rms),
// then one cvt+f64 add per pair -- identical arithmetic order to v2.
// FUSE3 (layer 2): epilogue computes the layer-3 assignment in-register.
// ---------------------------------------------------------------------------
template <int NCB, int NOUT, bool RELU, bool FUSE3, typename OutT>
__global__ __launch_bounds__(256) void accum_f64(
    const float* __restrict__ lut, const uint32_t* __restrict__ idxp,
    const float* __restrict__ scale, const float* __restrict__ bias,
    const float* __restrict__ c3cent, uint8_t* __restrict__ i3b,
    OutT* __restrict__ out) {
  __shared__ float s_lut[2 * 2048];   // 16 KB: 2 bufs x (8 cb x 16 k x 16 out)
  __shared__ float  c3f[4][16][4];
  __shared__ float  c3c2f[4][16];
  __shared__ double c3d[4][16][4];
  __shared__ double c3c2d[4][16];
  const int t = threadIdx.x;
  const int lane = t & 63;
  const int q = t >> 6;                 // channel quad 0..3 (wave id)
  const int p = blockIdx.x * 64 + lane; // 98*64 = 6272 = BP exactly
  const int o_base = blockIdx.y * 16;
  if (FUSE3 && t < 64) {
    int cb_l = t >> 4, k = t & 15;
    const float4 cf = *(const float4*)(c3cent + ((size_t)(blockIdx.y * 4 + cb_l)) * 64 + k * 4);
    c3f[cb_l][k][0] = cf.x; c3f[cb_l][k][1] = cf.y;
    c3f[cb_l][k][2] = cf.z; c3f[cb_l][k][3] = cf.w;
    double d0 = (double)cf.x, d1 = (double)cf.y, d2 = (double)cf.z, d3 = (double)cf.w;
    c3d[cb_l][k][0] = d0; c3d[cb_l][k][1] = d1;
    c3d[cb_l][k][2] = d2; c3d[cb_l][k][3] = d3;
    double s = 0.0; s += d0 * d0; s += d1 * d1; s += d2 * d2; s += d3 * d3;
    c3c2d[cb_l][k] = s;
    float s32 = 0.f; s32 += cf.x * cf.x; s32 += cf.y * cf.y;
    s32 += cf.z * cf.z; s32 += cf.w * cf.w;
    c3c2f[cb_l][k] = s32;
  }
  __syncthreads();   // c3 visible to all; full drain BEFORE any DMA in flight

  // DMA source for this thread's two slots: s0 = t -> (cb=t>>6, q=(t>>4)&3,
  // k=t&15); s1 = t+256 -> cb+4, same q,k (so src1 = src0 + 64*NOUT).
  const float* src0 = lut + ((size_t)(t >> 6) * 16 + (t & 15)) * NOUT
                          + o_base + ((t >> 4) & 3) * 4;
  // Wave-uniform LDS dests (HW adds lane*16B): slots [w*64) and [256+w*64).
  float* dst0 = s_lut + (t >> 6) * 256;
  constexpr int NCHUNK = NCB / 8;
  constexpr size_t CSTRIDE = (size_t)128 * NOUT;   // 8 cb * 16 k rows / chunk
  double a0 = 0, a1 = 0, a2 = 0, a3 = 0;
  // prologue: chunk 0 -> buf 0
  dma16(src0, dst0);
  dma16(src0 + 64 * NOUT, dst0 + 1024);
#pragma unroll 1
  for (int ch = 0; ch < NCHUNK; ch++) {
    const uint32_t w = idxp[(size_t)ch * BP + p];
    __builtin_amdgcn_sched_barrier(0);   // pin: idx load BEFORE next DMAs
    if (ch + 1 < NCHUNK) {
      const float* s = src0 + (size_t)(ch + 1) * CSTRIDE;
      float* d = dst0 + ((ch + 1) & 1) * 2048;
      dma16(s, d);
      dma16(s + 64 * NOUT, d + 1024);
      __builtin_amdgcn_sched_barrier(0);
      // wait chunk ch's DMA + idx word; leave chunk ch+1's 2 DMAs in flight
      asm volatile("s_waitcnt vmcnt(2)" ::: "memory");
    } else {
      asm volatile("s_waitcnt vmcnt(0)" ::: "memory");
    }
    __builtin_amdgcn_sched_barrier(0);
    __builtin_amdgcn_s_barrier();        // all waves' chunk-ch slots landed
    __builtin_amdgcn_sched_barrier(0);
    const float* buf = s_lut + (ch & 1) * 2048 + q * 64;
#pragma unroll
    for (int j = 0; j < 4; j++) {        // cb pair (2j, 2j+1) within chunk
      int i0 = (int)((w >> (8 * j)) & 15u);
      int i1 = (int)((w >> (8 * j + 4)) & 15u);
      const float4 va = *(const float4*)(buf + (2 * j) * 256 + i0 * 4);
      const float4 vb = *(const float4*)(buf + (2 * j + 1) * 256 + i1 * 4);
      float s0 = va.x + vb.x, s1 = va.y + vb.y;
      float s2 = va.z + vb.z, s3 = va.w + vb.w;
      a0 += (double)s0; a1 += (double)s1; a2 += (double)s2; a3 += (double)s3;
    }
    __builtin_amdgcn_sched_barrier(0);
    __builtin_amdgcn_s_barrier();        // reads done before buf overwrite
  }
  const unsigned b = (unsigned)p / 196u;
  const unsigned pr = (unsigned)p - b * 196u;
  const int o = o_base + q * 4;
  const float4 sc = *(const float4*)(scale + o);
  const float4 bs = *(const float4*)(bias + o);
  double r0 = a0 * (double)sc.x + (double)bs.x;
  double r1 = a1 * (double)sc.y + (double)bs.y;
  double r2 = a2 * (double)sc.z + (double)bs.z;
  double r3 = a3 * (double)sc.w + (double)bs.w;
  if (RELU) {
    r0 = fmax(r0, 0.0); r1 = fmax(r1, 0.0);
    r2 = fmax(r2, 0.0); r3 = fmax(r3, 0.0);
  }
  if (FUSE3) {
    // layer-3 assignment for codebook cb3 = blockIdx.y*4 + q (this thread's 4 ch)
    const int cb_l = q;
    float x0 = (float)r0, x1 = (float)r1, x2 = (float)r2, x3 = (float)r3;
    float best = 1e30f, sec = 1e30f; int bi = 0;
#pragma unroll
    for (int k = 0; k < 16; k++) {
      const float4 c = *(const float4*)&c3f[cb_l][k][0];
      float dot = x0 * c.x;
      dot = fmaf(x1, c.y, dot);
      dot = fmaf(x2, c.z, dot);
      dot = fmaf(x3, c.w, dot);
      float dist = fmaf(-2.f, dot, c3c2f[cb_l][k]);
      if (dist < best) { sec = best; best = dist; bi = k; }
      else sec = fminf(sec, dist);
    }
    if (__any(sec - best < 1e-3f)) {
      double bb = 1e300; int bi64 = 0;
#pragma unroll
      for (int k = 0; k < 16; k++) {
        double dot = 0.0;
        dot = fma(r0, c3d[cb_l][k][0], dot);
        dot = fma(r1, c3d[cb_l][k][1], dot);
        dot = fma(r2, c3d[cb_l][k][2], dot);
        dot = fma(r3, c3d[cb_l][k][3], dot);
        double dist = c3c2d[cb_l][k] - 2.0 * dot;
        if (dist < bb) { bb = dist; bi64 = k; }   // strict <: first-min
      }
      bi = bi64;
    }
    i3b[(size_t)p * 64 + blockIdx.y * 4 + q] = (uint8_t)bi;
  } else {
    OutT* op = out + ((size_t)b * NOUT + o) * PP + pr;
    op[0 * PP] = (OutT)r0; op[1 * PP] = (OutT)r1;
    op[2 * PP] = (OutT)r2; op[3 * PP] = (OutT)r3;
  }
}

// ---------------------------------------------------------------------------
// accum3: final layer (no downstream argmin). f32 LUT -> f16 staged in-register;
// packed v_pk_add_f16 inner loop, partials flushed to f32 every 8 codebooks.
// Index read: one dwordx4 of bytes per chunk from i3b[p][cb]. Rows 40 halfs
// (80 B): bank-quad (5*idx+h)%8 bijective -> 2-way = free.
// grid (49, 64), block 256 (4 waves): 128 positions x 16 channels.
// ---------------------------------------------------------------------------
__global__ __launch_bounds__(256) void accum3_f16(
    const float* __restrict__ lut, const uint8_t* __restrict__ i3b,
    const float* __restrict__ scale, const float* __restrict__ bias,
    const float* __restrict__ res, float* __restrict__ out) {
  __shared__ half_t s16[16 * 640];   // 20 KB
  const int t = threadIdx.x;
  const int lane = t & 63;
  const int wave = t >> 6;           // 0..3
  const int h = wave & 1;            // channel half (8 f16 ch)
  const int pg = wave >> 1;          // 0..1
  const int p = blockIdx.x * 128 + pg * 64 + lane;
  const int o_base = blockIdx.y * 16;
  // staging slots s0=t, s1=t+256 of 512: (cb=s>>5, k=(s>>1)&15, hh=s&1)
  const int s0 = t, s1 = t + 256;
  const int cA = s0 >> 5, kA = (s0 >> 1) & 15, hA = s0 & 1;
  const int cB = s1 >> 5, kB = (s1 >> 1) & 15, hB = s1 & 1;
  const size_t cs = (size_t)16 * 16 * 1024;     // 16 cb per chunk (f32 elems)
  constexpr int NCHUNK = 4;
  float acc[8];
#pragma unroll
  for (int i = 0; i < 8; i++) acc[i] = 0.f;
  for (int ch = 0; ch < NCHUNK; ch++) {
    __syncthreads();
    const uint4 iw = *(const uint4*)(i3b + (size_t)p * 64 + ch * 16);
    {
      const float* gA = lut + (size_t)ch * cs + ((size_t)cA * 16 + kA) * 1024 + o_base + hA * 8;
      const float* gB = lut + (size_t)ch * cs + ((size_t)cB * 16 + kB) * 1024 + o_base + hB * 8;
      float4 a0 = *(const float4*)gA;
      float4 a1 = *(const float4*)(gA + 4);
      float4 b0 = *(const float4*)gB;
      float4 b1 = *(const float4*)(gB + 4);
      half8v va, vb;
      va[0] = (half_t)a0.x; va[1] = (half_t)a0.y; va[2] = (half_t)a0.z; va[3] = (half_t)a0.w;
      va[4] = (half_t)a1.x; va[5] = (half_t)a1.y; va[6] = (half_t)a1.z; va[7] = (half_t)a1.w;
      vb[0] = (half_t)b0.x; vb[1] = (half_t)b0.y; vb[2] = (half_t)b0.z; vb[3] = (half_t)b0.w;
      vb[4] = (half_t)b1.x; vb[5] = (half_t)b1.y; vb[6] = (half_t)b1.z; vb[7] = (half_t)b1.w;
      *(half8v*)(s16 + cA * 640 + kA * 40 + hA * 8) = va;
      *(half8v*)(s16 + cB * 640 + kB * 40 + hB * 8) = vb;
    }
    __syncthreads();
#pragma unroll
    for (int grp = 0; grp < 2; grp++) {   // 8 cb per f32 flush
      uint32_t wa = grp ? iw.z : iw.x;
      uint32_t wb = grp ? iw.w : iw.y;
      half2v p0 = 0, p1 = 0, p2 = 0, p3 = 0;
#pragma unroll
      for (int j = 0; j < 8; j++) {
        uint32_t w = (j < 4) ? wa : wb;
        int idx = (int)((w >> ((j & 3) * 8)) & 15u);
        int cb_l = grp * 8 + j;
        const half8v v = *(const half8v*)(s16 + cb_l * 640 + idx * 40 + h * 8);
        const half2v* vp = (const half2v*)&v;
        p0 += vp[0]; p1 += vp[1]; p2 += vp[2]; p3 += vp[3];
      }
      acc[0] += (float)p0[0]; acc[1] += (float)p0[1];
      acc[2] += (float)p1[0]; acc[3] += (float)p1[1];
      acc[4] += (float)p2[0]; acc[5] += (float)p2[1];
      acc[6] += (float)p3[0]; acc[7] += (float)p3[1];
    }
  }
  const unsigned b = (unsigned)p / 196u;
  const unsigned pr = (unsigned)p - b * 196u;
  const int o = o_base + h * 8;
  const float* rp = res + ((size_t)b * 1024 + o) * PP + pr;
  float* op = out + ((size_t)b * 1024 + o) * PP + pr;
#pragma unroll
  for (int i = 0; i < 8; i++) {
    float v = acc[i] * scale[o + i] + bias[o + i] + rp[(size_t)i * PP];
    op[(size_t)i * PP] = fmaxf(v, 0.f);
  }
}

// ---------------------------------------------------------------------------

extern "C" void kernel_launch(void* const* d_in, const int* in_sizes, int n_in,
                              void* d_out, int out_size, void* d_ws, size_t ws_size,
                              hipStream_t stream) {
  const float* x   = (const float*)d_in[0];   // [32,1024,14,14]
  const float* c1c = (const float*)d_in[1];
  const float* c1l = (const float*)d_in[2];
  const float* c1s = (const float*)d_in[3];
  const float* c1b = (const float*)d_in[4];
  const float* c2c = (const float*)d_in[5];
  const float* c2l = (const float*)d_in[6];
  const float* c2s = (const float*)d_in[7];
  const float* c2b = (const float*)d_in[8];
  const float* c3c = (const float*)d_in[9];
  const float* c3l = (const float*)d_in[10];  // [64,16,1024]
  const float* c3s = (const float*)d_in[11];
  const float* c3b = (const float*)d_in[12];

  const size_t sz_i1  = (size_t)32 * BP * 4;      // 802,816 B
  const size_t sz_i2  = (size_t)32 * BP * 4;
  const size_t sz_i3b = (size_t)BP * 64;          // 401,408 B (byte indices)
  const size_t sz_o64 = (size_t)BP * 256 * 8;     // 12.85 MB

  char* w = (char*)d_ws;
  uint32_t* i1 = (uint32_t*)w; w += sz_i1;
  uint32_t* i2 = (uint32_t*)w; w += sz_i2;
  uint8_t* i3b = (uint8_t*)w;  w += sz_i3b;
  double* out1;
  if (ws_size >= (size_t)(w - (char*)d_ws) + sz_o64) {
    out1 = (double*)w;
  } else {
    // d_out (25.69 MB f32) holds one 12.85 MB f64 array in its first half;
    // accum3 (final) reads only i3b/x/c3l, then overwrites all of d_out.
    out1 = (double*)d_out;
  }

  const dim3 blkA(256), blkC(256);
  // layer 1: 1x1, 256 codebooks (dsub=4) over 1024 input channels
  assign_1x1<float><<<dim3(25, 32), blkA, 0, stream>>>(x, c1c, i1, 1024);
  accum_f64<256, 256, true, false, double><<<dim3(98, 16), blkC, 0, stream>>>(
      c1l, i1, c1s, c1b, nullptr, nullptr, out1);
  // layer 2: 3x3, 256 codebooks (dsub=9); epilogue fuses the layer-3 assign
  assign_3x3<<<dim3(25, 32), blkA, 0, stream>>>(out1, c2c, i2);
  accum_f64<256, 256, true, true, double><<<dim3(98, 16), blkC, 0, stream>>>(
      c2l, i2, c2s, c2b, c3c, i3b, nullptr);
  // layer 3: 64 codebooks over 256 channels; fused residual + relu
  accum3_f16<<<dim3(49, 64), blkC, 0, stream>>>(
      c3l, i3b, c3s, c3b, x, (float*)d_out);
}